// Round 3
// baseline (95.556 us; speedup 1.0000x reference)
//
#include <hip/hip_runtime.h>
#include <math.h>

#define NB 131072
#define NSTEPS 30

typedef float  float4v __attribute__((ext_vector_type(4)));
typedef short  short4v __attribute__((ext_vector_type(4)));

#define MFMA16 __builtin_amdgcn_mfma_f32_16x16x16bf16_1k

static __device__ __forceinline__ unsigned fb(float f) {
    union { float f; unsigned u; } c; c.f = f; return c.u;
}
static __device__ __forceinline__ float fu(unsigned u) {
    union { unsigned u; float f; } c; c.u = u; return c.f;
}

struct bfpair { short4v hi, lo; };

// Truncation split, pure C++ (no inline asm):
//   hi = trunc_bf16(v); lo_exact = v - hi (EXACT in f32); lo = trunc_bf16(lo_exact)
// v = hi + lo + err, |err| <= 2^-16 |v|.
static __device__ __forceinline__ bfpair split4(float4v v) {
    unsigned u0 = fb(v[0]), u1 = fb(v[1]), u2 = fb(v[2]), u3 = fb(v[3]);
    float l0 = v[0] - fu(u0 & 0xffff0000u);
    float l1 = v[1] - fu(u1 & 0xffff0000u);
    float l2 = v[2] - fu(u2 & 0xffff0000u);
    float l3 = v[3] - fu(u3 & 0xffff0000u);
    union { unsigned u[2]; short4v s; } H, L;
    H.u[0] = (u0 >> 16) | (u1 & 0xffff0000u);
    H.u[1] = (u2 >> 16) | (u3 & 0xffff0000u);
    L.u[0] = (fb(l0) >> 16) | (fb(l1) & 0xffff0000u);
    L.u[1] = (fb(l2) >> 16) | (fb(l3) & 0xffff0000u);
    bfpair P; P.hi = H.s; P.lo = L.s; return P;
}

static __device__ __forceinline__ float sigmoid_f(float p) {
    return __builtin_amdgcn_rcpf(1.0f + __expf(-p));
}

__global__ __launch_bounds__(256, 3) void pcnet_kernel(
    const float* __restrict__ x,    // [B,16]
    const float* __restrict__ W1,   // [64,16]
    const float* __restrict__ b1,   // [64]
    const float* __restrict__ W2,   // [16,64]
    const float* __restrict__ b2,   // [16]
    const float* __restrict__ x1i,  // [B,64]
    const float* __restrict__ x2i,  // [B,16]
    float* __restrict__ out)        // [B,64] x1 then [B,16] x2
{
    const int tid  = blockIdx.x * 256 + threadIdx.x;
    const int wave = tid >> 6;
    const int lane = threadIdx.x & 63;
    const int g = lane >> 4;          // lane group 0..3
    const int q = lane & 15;          // 16x16 row/col index
    const int r = wave * 16 + q;      // batch row handled by this lane

    // ---- static split fragments ----
    // GEMM1 A-operand: W2 chunk c, elem j = W2[q][16c+4g+j]
    bfpair a_w2[4];
#pragma unroll
    for (int c = 0; c < 4; ++c) {
        float4v w = *(const float4v*)(W2 + q * 64 + 16 * c + 4 * g);
        a_w2[c] = split4(w);
    }
    // GEMM2 A-operand: tile t, elem j = 0.2 * W2[4g+j][16t+q]   (W2^T, pre-scaled)
    bfpair a_w2t[4];
#pragma unroll
    for (int t = 0; t < 4; ++t) {
        float4v e;
        e[0] = 0.2f * W2[(4 * g + 0) * 64 + 16 * t + q];
        e[1] = 0.2f * W2[(4 * g + 1) * 64 + 16 * t + q];
        e[2] = 0.2f * W2[(4 * g + 2) * 64 + 16 * t + q];
        e[3] = 0.2f * W2[(4 * g + 3) * 64 + 16 * t + q];
        a_w2t[t] = split4(e);
    }
    // b2 in GEMM1 output layout: acc[reg] = b2[4g+reg]
    const float4v b2f = *(const float4v*)(b2 + 4 * g);

    // ---- mu1 = sigmoid(x @ W1^T + b1), kept pre-scaled by 0.2, in X1 layout ----
    float4v xv = *(const float4v*)(x + r * 16 + 4 * g);
    bfpair bx = split4(xv);
    float4v mu1s[4];
#pragma unroll
    for (int t = 0; t < 4; ++t) {
        float4v aw = *(const float4v*)(W1 + (16 * t + q) * 16 + 4 * g);
        bfpair a1 = split4(aw);
        float4v acc = *(const float4v*)(b1 + 16 * t + 4 * g);
        acc = MFMA16(a1.hi, bx.hi, acc, 0, 0, 0);
        acc = MFMA16(a1.hi, bx.lo, acc, 0, 0, 0);
        acc = MFMA16(a1.lo, bx.hi, acc, 0, 0, 0);
#pragma unroll
        for (int j = 0; j < 4; ++j)
            mu1s[t][j] = 0.2f * sigmoid_f(acc[j]);
    }

    // ---- state (fp32 masters) ----
    float4v x1v[4];
#pragma unroll
    for (int t = 0; t < 4; ++t)
        x1v[t] = *(const float4v*)(x1i + r * 64 + 16 * t + 4 * g);
    float4v x2v = *(const float4v*)(x2i + r * 16 + 4 * g);

    // ---- 30 inference steps, zero memory traffic, zero cross-lane traffic ----
#pragma unroll 1
    for (int s = 0; s < NSTEPS; ++s) {
        // split X1 -> hi/lo bf16 B-fragments
        bfpair bx1[4];
#pragma unroll
        for (int c = 0; c < 4; ++c)
            bx1[c] = split4(x1v[c]);

        // GEMM1: mu2pre^T = W2 @ X1^T + b2 (acc init); hh + hl + lh products
        float4v p = b2f;
#pragma unroll
        for (int c = 0; c < 4; ++c)
            p = MFMA16(a_w2[c].hi, bx1[c].hi, p, 0, 0, 0);
#pragma unroll
        for (int c = 0; c < 4; ++c)
            p = MFMA16(a_w2[c].hi, bx1[c].lo, p, 0, 0, 0);
#pragma unroll
        for (int c = 0; c < 4; ++c)
            p = MFMA16(a_w2[c].lo, bx1[c].hi, p, 0, 0, 0);

        // sigmoid, d = e2*mu2*(1-mu2), x2 update  (all lane-local)
        float4v dv;
#pragma unroll
        for (int j = 0; j < 4; ++j) {
            float mu2 = sigmoid_f(p[j]);
            float e2  = x2v[j] - mu2;
            float mm  = mu2 - mu2 * mu2;               // mu2*(1-mu2)
            dv[j] = e2 * mm;
            x2v[j] = x2v[j] + 0.2f * (mu2 - x2v[j]);   // x2 <- 0.8 x2 + 0.2 mu2
        }
        bfpair bd = split4(dv);

        // GEMM2: R = 0.2*(W2^T @ D) + 0.2*mu1 (acc init); x1 <- 0.8 x1 + R
#pragma unroll
        for (int t = 0; t < 4; ++t) {
            float4v rg = mu1s[t];
            rg = MFMA16(a_w2t[t].hi, bd.hi, rg, 0, 0, 0);
            rg = MFMA16(a_w2t[t].hi, bd.lo, rg, 0, 0, 0);
            rg = MFMA16(a_w2t[t].lo, bd.hi, rg, 0, 0, 0);
#pragma unroll
            for (int j = 0; j < 4; ++j)
                x1v[t][j] = fmaf(0.8f, x1v[t][j], rg[j]);
        }
    }

    // ---- store results ----
#pragma unroll
    for (int t = 0; t < 4; ++t)
        *(float4v*)(out + r * 64 + 16 * t + 4 * g) = x1v[t];
    *(float4v*)(out + (size_t)NB * 64 + r * 16 + 4 * g) = x2v;
}

extern "C" void kernel_launch(void* const* d_in, const int* in_sizes, int n_in,
                              void* d_out, int out_size, void* d_ws, size_t ws_size,
                              hipStream_t stream) {
    const float* x   = (const float*)d_in[0];
    const float* W1  = (const float*)d_in[1];
    const float* b1  = (const float*)d_in[2];
    const float* W2  = (const float*)d_in[3];
    const float* b2  = (const float*)d_in[4];
    const float* x1i = (const float*)d_in[5];
    const float* x2i = (const float*)d_in[6];
    float* out = (float*)d_out;

    dim3 grid(NB / 64);   // 16 rows per wave, 4 waves per block
    dim3 block(256);
    pcnet_kernel<<<grid, block, 0, stream>>>(x, W1, b1, W2, b2, x1i, x2i, out);
}